// Round 11
// baseline (145.093 us; speedup 1.0000x reference)
//
#include <hip/hip_runtime.h>

#define N_NODES 16384
#define N_EDGES 262144
#define D 256
#define B_GRAPHS 32
#define NODES_PER_GRAPH 512   // N_NODES / B_GRAPHS
#define MAXDEG 64             // Poisson(16): P(deg>64) ~ 1e-17
#define L2CAP 2080            // 32 roots + 32*64 max captured srcs

typedef unsigned short u16;
typedef __attribute__((ext_vector_type(8)))  short bf16x8;
typedef __attribute__((ext_vector_type(16))) float f32x16;
typedef __attribute__((ext_vector_type(8)))  unsigned short u16x8;
typedef __attribute__((ext_vector_type(4)))  unsigned short u16x4;

static __device__ __forceinline__ u16 f2bf(float f) {
    unsigned int u = __float_as_uint(f);
    unsigned int r = (u + 0x7FFFu + ((u >> 16) & 1u)) >> 16;   // RNE
    return (u16)r;
}
static __device__ __forceinline__ float bf2f(u16 h) {
    return __uint_as_float(((unsigned int)h) << 16);
}
// involution swizzle on byte offsets within an 8KB [128 rows x 64B] LDS array
static __device__ __forceinline__ int swz(int a) {
    return a ^ (((a >> 7) & 3) << 4);
}
static __device__ __forceinline__ void gload16(const void* g, void* l) {
    __builtin_amdgcn_global_load_lds(
        (const __attribute__((address_space(1))) unsigned int*)g,
        (__attribute__((address_space(3))) unsigned int*)l, 16, 0, 0);
}

// ---------------------------------------------------------------------------
// prep: [0,2048) split x; [2048,2144) W transpose+split; [2144,2208) zero cnt;
//       [2208,2272) init l2 flags (roots pre-set); [2272] seed l2 list
// ---------------------------------------------------------------------------
__global__ __launch_bounds__(256) void prep_kernel(
    const float* __restrict__ x, const float* __restrict__ Wl,
    const float* __restrict__ Wr,
    u16* __restrict__ Xhi, u16* __restrict__ Xlo,
    u16* __restrict__ WtL_hi, u16* __restrict__ WtL_lo,
    u16* __restrict__ WtR_hi, u16* __restrict__ WtR_lo,
    int* __restrict__ cnt, int* __restrict__ flags,
    int* __restrict__ l2list, int* __restrict__ l2cnt)
{
    __shared__ float S[64][68];
    const int bid = blockIdx.x;
    const int t = threadIdx.x;
    if (bid < 2048) {
        size_t e0 = ((size_t)bid * 256 + t) * 8;
        float4 v0 = *(const float4*)&x[e0];
        float4 v1 = *(const float4*)&x[e0 + 4];
        float xs[8] = {v0.x, v0.y, v0.z, v0.w, v1.x, v1.y, v1.z, v1.w};
        u16x8 H, L;
        #pragma unroll
        for (int j = 0; j < 8; ++j) {
            u16 h = f2bf(xs[j]);
            H[j] = h; L[j] = f2bf(xs[j] - bf2f(h));
        }
        *(u16x8*)&Xhi[e0] = H;
        *(u16x8*)&Xlo[e0] = L;
    } else if (bid < 2144) {
        int mb = bid - 2048;
        int mat = mb / 16, sub = mb % 16;
        int kt = (sub >> 2) * 64, nt = (sub & 3) * 64;
        const float* src = (mat < 3) ? Wl + (size_t)mat * 65536 : Wr + (size_t)(mat - 3) * 65536;
        u16* dhi = (mat < 3) ? WtL_hi + (size_t)mat * 65536 : WtR_hi + (size_t)(mat - 3) * 65536;
        u16* dlo = (mat < 3) ? WtL_lo + (size_t)mat * 65536 : WtR_lo + (size_t)(mat - 3) * 65536;
        int r = t >> 2, c0 = (t & 3) * 16;
        #pragma unroll
        for (int j = 0; j < 4; ++j) {
            float4 v = *(const float4*)&src[(size_t)(kt + r) * 256 + nt + c0 + j * 4];
            *(float4*)&S[r][c0 + j * 4] = v;
        }
        __syncthreads();
        int n = t >> 2, kc = (t & 3) * 16;
        u16x8 h0, h1, l0, l1;
        #pragma unroll
        for (int j = 0; j < 8; ++j) {
            float xv = S[kc + j][n];
            u16 h = f2bf(xv);
            h0[j] = h; l0[j] = f2bf(xv - bf2f(h));
            float y = S[kc + 8 + j][n];
            u16 g = f2bf(y);
            h1[j] = g; l1[j] = f2bf(y - bf2f(g));
        }
        size_t o = (size_t)(nt + n) * 256 + kt + kc;
        *(u16x8*)&dhi[o] = h0; *(u16x8*)&dhi[o + 8] = h1;
        *(u16x8*)&dlo[o] = l0; *(u16x8*)&dlo[o + 8] = l1;
    } else if (bid < 2208) {
        cnt[(bid - 2144) * 256 + t] = 0;
    } else if (bid < 2272) {
        int i = (bid - 2208) * 256 + t;
        flags[i] = ((i & (NODES_PER_GRAPH - 1)) == 0) ? 1 : 0;  // roots pre-marked
    } else {
        if (t < B_GRAPHS) l2list[t] = t * NODES_PER_GRAPH;
        if (t == 0) *l2cnt = B_GRAPHS;
    }
}

// ---------------------------------------------------------------------------
// bucket fill + L2-active capture (srcs of edges into roots, deduped)
// ---------------------------------------------------------------------------
__global__ __launch_bounds__(256) void fill_bucket_kernel(const int* __restrict__ edge,
                                                          int* __restrict__ cnt,
                                                          int* __restrict__ col,
                                                          int* __restrict__ flags,
                                                          int* __restrict__ l2list,
                                                          int* __restrict__ l2cnt) {
    int e = blockIdx.x * 256 + threadIdx.x;
    int dst = edge[N_EDGES + e];
    int src = edge[e];
    int slot = atomicAdd(&cnt[dst], 1);
    if (slot < MAXDEG) {
        col[dst * MAXDEG + slot] = src;
        if ((dst & (NODES_PER_GRAPH - 1)) == 0) {     // dst is a root
            if (atomicCAS(&flags[src], 0, 1) == 0) {
                int p = atomicAdd(l2cnt, 1);
                if (p < L2CAP) l2list[p] = src;
            }
        }
    }
}

// ---------------------------------------------------------------------------
// per-node mean-aggregate (64-lane wave), gathers HI only, writes hi/lo at
// the node's row in Agg
// ---------------------------------------------------------------------------
static __device__ __forceinline__ void agg_node(const u16* __restrict__ Xs,
                                                const int* __restrict__ cnt,
                                                const int* __restrict__ col,
                                                int node, int lane,
                                                u16* __restrict__ Ah,
                                                u16* __restrict__ Al) {
    int c = cnt[node];
    if (c > MAXDEG) c = MAXDEG;
    int my = (lane < c) ? col[node * MAXDEG + lane] : 0;
    float a0 = 0.f, a1 = 0.f, a2 = 0.f, a3 = 0.f;
    int j = 0;
    for (; j + 8 <= c; j += 8) {
        u16x4 v[8];
        #pragma unroll
        for (int q = 0; q < 8; ++q) {
            int s = __shfl(my, j + q);
            v[q] = *(const u16x4*)&Xs[(size_t)s * D + lane * 4];
        }
        #pragma unroll
        for (int q = 0; q < 8; ++q) {
            a0 += bf2f(v[q][0]); a1 += bf2f(v[q][1]);
            a2 += bf2f(v[q][2]); a3 += bf2f(v[q][3]);
        }
    }
    for (; j < c; ++j) {
        int s = __shfl(my, j);
        u16x4 v = *(const u16x4*)&Xs[(size_t)s * D + lane * 4];
        a0 += bf2f(v[0]); a1 += bf2f(v[1]); a2 += bf2f(v[2]); a3 += bf2f(v[3]);
    }
    float id = 1.0f / (float)(c < 1 ? 1 : c);
    float m[4] = {a0 * id, a1 * id, a2 * id, a3 * id};
    u16x4 H, L;
    #pragma unroll
    for (int q = 0; q < 4; ++q) {
        u16 h = f2bf(m[q]);
        H[q] = h; L[q] = f2bf(m[q] - bf2f(h));
    }
    *(u16x4*)&Ah[(size_t)node * D + lane * 4] = H;
    *(u16x4*)&Al[(size_t)node * D + lane * 4] = L;
}

// ---------------------------------------------------------------------------
// full-graph aggregation (layer 1)
// ---------------------------------------------------------------------------
__global__ __launch_bounds__(256) void agg_kernel(const u16* __restrict__ Xhi,
                                                  const int* __restrict__ cnt,
                                                  const int* __restrict__ col,
                                                  u16* __restrict__ Agghi,
                                                  u16* __restrict__ Agglo) {
    int node = blockIdx.x * 4 + (threadIdx.x >> 6);
    agg_node(Xhi, cnt, col, node, threadIdx.x & 63, Agghi, Agglo);
}

// ---------------------------------------------------------------------------
// full MFMA dual GEMM (layer 1) — R4/R6/R8 proven
// ---------------------------------------------------------------------------
__global__ __launch_bounds__(256) void gemm_mfma_kernel(
    const u16* __restrict__ Xhi,   const u16* __restrict__ Xlo,
    const u16* __restrict__ Agghi, const u16* __restrict__ Agglo,
    const u16* __restrict__ WtRhi, const u16* __restrict__ WtRlo,
    const u16* __restrict__ WtLhi, const u16* __restrict__ WtLlo,
    const float* __restrict__ bias,
    u16* __restrict__ Xohi, u16* __restrict__ Xolo)
{
    __shared__ u16 lds[2][4][4096];   // [buf][Ahi,Alo,Bhi,Blo][8KB]

    const int tid  = threadIdx.x;
    const int w    = tid >> 6, lane = tid & 63;
    const int wm   = w >> 1, wn = w & 1;
    const int bid  = blockIdx.x;
    const int m0   = (bid >> 1) * 128;
    const int n0   = (bid & 1) * 128;

    f32x16 acc[4];
    #pragma unroll
    for (int f = 0; f < 4; ++f)
        #pragma unroll
        for (int j = 0; j < 16; ++j) acc[f][j] = 0.f;

    const int r32 = lane & 31;
    const int khb = (lane >> 5) * 16;

    auto stage = [&](int buf, int tt) {
        const u16* src; int rbase;
        const int k0 = (tt & 7) * 32;
        const bool ph2 = tt >= 8;
        if      (w == 0) { src = ph2 ? Agghi : Xhi;  rbase = m0; }
        else if (w == 1) { src = ph2 ? Agglo : Xlo;  rbase = m0; }
        else if (w == 2) { src = ph2 ? WtLhi : WtRhi; rbase = n0; }
        else             { src = ph2 ? WtLlo : WtRlo; rbase = n0; }
        char* base = (char*)&lds[buf][w][0];
        #pragma unroll
        for (int i = 0; i < 8; ++i) {
            int o = i * 1024 + lane * 16;
            int a = swz(o);
            const u16* g = src + (size_t)(rbase + (a >> 6)) * D + k0 + ((a & 63) >> 1);
            gload16(g, base + i * 1024);
        }
    };

    auto compute = [&](int buf) {
        const char* Ah = (const char*)&lds[buf][0][0];
        const char* Al = (const char*)&lds[buf][1][0];
        const char* Bh = (const char*)&lds[buf][2][0];
        const char* Bl = (const char*)&lds[buf][3][0];
        #pragma unroll
        for (int s = 0; s < 2; ++s) {
            const int cb = s * 32 + khb;
            const int ra0 = wm * 64 + r32, ra1 = ra0 + 32;
            const int rb0 = wn * 64 + r32, rb1 = rb0 + 32;
            bf16x8 ah0 = *(const bf16x8*)(Ah + swz(ra0 * 64 + cb));
            bf16x8 ah1 = *(const bf16x8*)(Ah + swz(ra1 * 64 + cb));
            bf16x8 al0 = *(const bf16x8*)(Al + swz(ra0 * 64 + cb));
            bf16x8 al1 = *(const bf16x8*)(Al + swz(ra1 * 64 + cb));
            bf16x8 bh0 = *(const bf16x8*)(Bh + swz(rb0 * 64 + cb));
            bf16x8 bh1 = *(const bf16x8*)(Bh + swz(rb1 * 64 + cb));
            bf16x8 bl0 = *(const bf16x8*)(Bl + swz(rb0 * 64 + cb));
            bf16x8 bl1 = *(const bf16x8*)(Bl + swz(rb1 * 64 + cb));
            acc[0] = __builtin_amdgcn_mfma_f32_32x32x16_bf16(ah0, bh0, acc[0], 0, 0, 0);
            acc[1] = __builtin_amdgcn_mfma_f32_32x32x16_bf16(ah0, bh1, acc[1], 0, 0, 0);
            acc[2] = __builtin_amdgcn_mfma_f32_32x32x16_bf16(ah1, bh0, acc[2], 0, 0, 0);
            acc[3] = __builtin_amdgcn_mfma_f32_32x32x16_bf16(ah1, bh1, acc[3], 0, 0, 0);
            acc[0] = __builtin_amdgcn_mfma_f32_32x32x16_bf16(al0, bh0, acc[0], 0, 0, 0);
            acc[1] = __builtin_amdgcn_mfma_f32_32x32x16_bf16(al0, bh1, acc[1], 0, 0, 0);
            acc[2] = __builtin_amdgcn_mfma_f32_32x32x16_bf16(al1, bh0, acc[2], 0, 0, 0);
            acc[3] = __builtin_amdgcn_mfma_f32_32x32x16_bf16(al1, bh1, acc[3], 0, 0, 0);
            acc[0] = __builtin_amdgcn_mfma_f32_32x32x16_bf16(ah0, bl0, acc[0], 0, 0, 0);
            acc[1] = __builtin_amdgcn_mfma_f32_32x32x16_bf16(ah0, bl1, acc[1], 0, 0, 0);
            acc[2] = __builtin_amdgcn_mfma_f32_32x32x16_bf16(ah1, bl0, acc[2], 0, 0, 0);
            acc[3] = __builtin_amdgcn_mfma_f32_32x32x16_bf16(ah1, bl1, acc[3], 0, 0, 0);
        }
    };

    stage(0, 0);
    __syncthreads();
    int cur = 0;
    for (int t = 0; t < 16; ++t) {
        if (t < 15) stage(cur ^ 1, t + 1);
        compute(cur);
        __syncthreads();
        cur ^= 1;
    }

    #pragma unroll
    for (int fm = 0; fm < 2; ++fm) {
        #pragma unroll
        for (int fn = 0; fn < 2; ++fn) {
            const int colc = n0 + wn * 64 + fn * 32 + r32;
            const int rowb = m0 + wm * 64 + fm * 32 + 4 * (lane >> 5);
            const float bv = bias[colc];
            #pragma unroll
            for (int reg = 0; reg < 16; ++reg) {
                const int row = rowb + (reg & 3) + 8 * (reg >> 2);
                float v = acc[fm * 2 + fn][reg] + bv;
                u16 h = f2bf(v);
                Xohi[(size_t)row * D + colc] = h;
                Xolo[(size_t)row * D + colc] = f2bf(v - bf2f(h));
            }
        }
    }
}

// ---------------------------------------------------------------------------
// FUSED sparse layer: inline agg (16 waves x 2 rows) -> threadfence/sync ->
// 32-row-tile dual GEMM (R8-proven body). mode 0: rows from l2list (layer 2);
// mode 1: the 32 roots (layer 3). Intra-block dependency only.
// ---------------------------------------------------------------------------
__global__ __launch_bounds__(1024) void gemm_sparse_fused_kernel(
    const int* __restrict__ cnt, const int* __restrict__ col,
    const int* __restrict__ l2list, const int* __restrict__ l2cntp, int mode,
    const u16* __restrict__ Xh, const u16* __restrict__ Xl,
    u16* __restrict__ Ah, u16* __restrict__ Al,       // Agg scratch (written here)
    const u16* __restrict__ WRh, const u16* __restrict__ WRl,
    const u16* __restrict__ WLh, const u16* __restrict__ WLl,
    const float* __restrict__ bias,
    u16* __restrict__ Oh, u16* __restrict__ Ol)
{
    __shared__ __attribute__((aligned(16))) u16 As[2][32 * 40];   // 80B stride
    __shared__ __attribute__((aligned(16))) u16 Bs[2][256 * 40];
    __shared__ int rid[32];

    const int bid = blockIdx.x;
    const int t = threadIdx.x;
    const int w = t >> 6, lane = t & 63;

    if (mode == 0) {
        int nl2 = *l2cntp; if (nl2 > L2CAP) nl2 = L2CAP;
        if (bid * 32 >= nl2) return;
        if (t < 32) {
            int idx = bid * 32 + t;
            if (idx > nl2 - 1) idx = nl2 - 1;   // clamp-pad
            rid[t] = l2list[idx];
        }
    } else {
        if (t < 32) rid[t] = t * NODES_PER_GRAPH;
    }
    __syncthreads();

    // ---- inline aggregation for this tile's 32 rows (2 per wave) ----
    for (int i = w; i < 32; i += 16)
        agg_node(Xh, cnt, col, rid[i], lane, Ah, Al);
    __threadfence();      // drain/visibility for same-block global handoff
    __syncthreads();

    // ---- dual GEMM (R8-proven numerics) ----
    f32x16 acc;
    #pragma unroll
    for (int j = 0; j < 16; ++j) acc[j] = 0.f;

    for (int ph = 0; ph < 2; ++ph) {
        const u16* ah = ph ? Ah : Xh;
        const u16* al = ph ? Al : Xl;
        const u16* bh_ = ph ? WLh : WRh;
        const u16* bl_ = ph ? WLl : WRl;
        for (int k0 = 0; k0 < 8; ++k0) {
            __syncthreads();
            {
                int row = t >> 5, kk = t & 31;
                int rg = rid[row];
                As[0][row * 40 + kk] = ah[(size_t)rg * D + k0 * 32 + kk];
                As[1][row * 40 + kk] = al[(size_t)rg * D + k0 * 32 + kk];
            }
            {
                int n = t >> 2, kq = t & 3;
                *(u16x8*)&Bs[0][n * 40 + kq * 8] =
                    *(const u16x8*)&bh_[(size_t)n * D + k0 * 32 + kq * 8];
                *(u16x8*)&Bs[1][n * 40 + kq * 8] =
                    *(const u16x8*)&bl_[(size_t)n * D + k0 * 32 + kq * 8];
            }
            __syncthreads();
            if (w < 8) {
                #pragma unroll
                for (int s = 0; s < 2; ++s) {
                    int kb = s * 32 + (lane >> 5) * 16;
                    bf16x8 fah = *(const bf16x8*)((char*)&As[0][0] + (lane & 31) * 80 + kb);
                    bf16x8 fal = *(const bf16x8*)((char*)&As[1][0] + (lane & 31) * 80 + kb);
                    int n = w * 32 + (lane & 31);
                    bf16x8 fbh = *(const bf16x8*)((char*)&Bs[0][0] + n * 80 + kb);
                    bf16x8 fbl = *(const bf16x8*)((char*)&Bs[1][0] + n * 80 + kb);
                    acc = __builtin_amdgcn_mfma_f32_32x32x16_bf16(fah, fbh, acc, 0, 0, 0);
                    acc = __builtin_amdgcn_mfma_f32_32x32x16_bf16(fal, fbh, acc, 0, 0, 0);
                    acc = __builtin_amdgcn_mfma_f32_32x32x16_bf16(fah, fbl, acc, 0, 0, 0);
                }
            }
        }
    }
    __syncthreads();
    if (w < 8) {
        int colc = w * 32 + (lane & 31);
        float bv = bias[colc];
        #pragma unroll
        for (int reg = 0; reg < 16; ++reg) {
            int row = (reg & 3) + 8 * (reg >> 2) + 4 * (lane >> 5);
            int rg = rid[row];
            float v = acc[reg] + bv;
            u16 h = f2bf(v);
            Oh[(size_t)rg * D + colc] = h;
            Ol[(size_t)rg * D + colc] = f2bf(v - bf2f(h));
        }
    }
}

// ---------------------------------------------------------------------------
// MLP head: 32 blocks x 1024 threads (R4 proven)
// ---------------------------------------------------------------------------
__global__ __launch_bounds__(1024) void head_kernel(const u16* __restrict__ Xhi,
                                                    const u16* __restrict__ Xlo,
                                                    const float* __restrict__ Wh,
                                                    const float* __restrict__ bh,
                                                    const float* __restrict__ Wo,
                                                    const float* __restrict__ bo,
                                                    float* __restrict__ out) {
    __shared__ float h[D];
    __shared__ float part[4][D];
    const int b = blockIdx.x, t = threadIdx.x;
    if (t < D) {
        size_t idx = (size_t)(b * NODES_PER_GRAPH) * D + t;
        h[t] = bf2f(Xhi[idx]) + bf2f(Xlo[idx]);
    }
    __syncthreads();
    const int c = t & 255, kq = t >> 8;
    for (int l = 0; l < 3; ++l) {
        const float* W = (l < 2) ? Wh + (size_t)l * D * D : Wo;
        float acc = 0.f;
        #pragma unroll
        for (int k0 = 0; k0 < 64; k0 += 8) {
            float wv[8];
            #pragma unroll
            for (int j = 0; j < 8; ++j)
                wv[j] = W[(size_t)(kq * 64 + k0 + j) * D + c];
            #pragma unroll
            for (int j = 0; j < 8; ++j)
                acc += h[kq * 64 + k0 + j] * wv[j];
        }
        part[kq][c] = acc;
        __syncthreads();
        if (t < D) {
            float v = part[0][t] + part[1][t] + part[2][t] + part[3][t]
                    + ((l < 2) ? bh[(size_t)l * D + t] : bo[t]);
            if (l < 2) h[t] = fmaxf(v, 0.f);
            else       out[(size_t)b * D + t] = v;
        }
        __syncthreads();
    }
}

// ---------------------------------------------------------------------------
extern "C" void kernel_launch(void* const* d_in, const int* in_sizes, int n_in,
                              void* d_out, int out_size, void* d_ws, size_t ws_size,
                              hipStream_t stream) {
    const float* x    = (const float*)d_in[0];
    const int*   edge = (const int*)d_in[1];
    const float* Wl   = (const float*)d_in[2];
    const float* bl   = (const float*)d_in[3];
    const float* Wr   = (const float*)d_in[4];
    const float* Wh   = (const float*)d_in[5];
    const float* bh   = (const float*)d_in[6];
    const float* Wo   = (const float*)d_in[7];
    const float* bo   = (const float*)d_in[8];
    float* out = (float*)d_out;

    char* w = (char*)d_ws;
    auto alloc = [&](size_t bytes) {
        char* p = w;
        w += (bytes + 255) & ~(size_t)255;
        return p;
    };
    int* cnt    = (int*)alloc((size_t)N_NODES * 4);
    int* col    = (int*)alloc((size_t)N_NODES * MAXDEG * 4);
    int* flags  = (int*)alloc((size_t)N_NODES * 4);
    int* l2list = (int*)alloc((size_t)4096 * 4);
    int* l2cnt  = (int*)alloc(256);
    u16* Xh[2] = {(u16*)alloc((size_t)N_NODES * D * 2), (u16*)alloc((size_t)N_NODES * D * 2)};
    u16* Xl[2] = {(u16*)alloc((size_t)N_NODES * D * 2), (u16*)alloc((size_t)N_NODES * D * 2)};
    u16* Agghi = (u16*)alloc((size_t)N_NODES * D * 2);
    u16* Agglo = (u16*)alloc((size_t)N_NODES * D * 2);
    u16* WtLhi = (u16*)alloc((size_t)3 * 65536 * 2);
    u16* WtLlo = (u16*)alloc((size_t)3 * 65536 * 2);
    u16* WtRhi = (u16*)alloc((size_t)3 * 65536 * 2);
    u16* WtRlo = (u16*)alloc((size_t)3 * 65536 * 2);

    prep_kernel<<<2273, 256, 0, stream>>>(x, Wl, Wr, Xh[0], Xl[0],
                                          WtLhi, WtLlo, WtRhi, WtRlo,
                                          cnt, flags, l2list, l2cnt);
    fill_bucket_kernel<<<N_EDGES / 256, 256, 0, stream>>>(edge, cnt, col,
                                                          flags, l2list, l2cnt);
    // ---- layer 1: full graph ----
    agg_kernel<<<N_NODES / 4, 256, 0, stream>>>(Xh[0], cnt, col, Agghi, Agglo);
    gemm_mfma_kernel<<<256, 256, 0, stream>>>(
        Xh[0], Xl[0], Agghi, Agglo,
        WtRhi, WtRlo, WtLhi, WtLlo,
        bl, Xh[1], Xl[1]);
    // ---- layer 2: fused inline-agg + GEMM over captured rows ----
    gemm_sparse_fused_kernel<<<L2CAP / 32, 1024, 0, stream>>>(
        cnt, col, l2list, l2cnt, 0,
        Xh[1], Xl[1], Agghi, Agglo,
        WtRhi + 65536, WtRlo + 65536, WtLhi + 65536, WtLlo + 65536,
        bl + D, Xh[0], Xl[0]);
    // ---- layer 3: fused inline-agg + GEMM for the 32 roots ----
    gemm_sparse_fused_kernel<<<1, 1024, 0, stream>>>(
        cnt, col, l2list, l2cnt, 1,
        Xh[0], Xl[0], Agghi, Agglo,
        WtRhi + 2 * 65536, WtRlo + 2 * 65536, WtLhi + 2 * 65536, WtLlo + 2 * 65536,
        bl + 2 * D, Xh[1], Xl[1]);
    // ---- head ----
    head_kernel<<<B_GRAPHS, 1024, 0, stream>>>(Xh[1], Xl[1], Wh, bh, Wo, bo, out);
}

// Round 12
// 97.847 us; speedup vs baseline: 1.4829x; 1.4829x over previous
//
#include <hip/hip_runtime.h>

#define N_NODES 16384
#define N_EDGES 262144
#define D 256
#define B_GRAPHS 32
#define NODES_PER_GRAPH 512   // N_NODES / B_GRAPHS
#define MAXDEG 64             // Poisson(16): P(deg>64) ~ 1e-17

typedef unsigned short u16;
typedef __attribute__((ext_vector_type(8)))  short bf16x8;
typedef __attribute__((ext_vector_type(16))) float f32x16;
typedef __attribute__((ext_vector_type(8)))  unsigned short u16x8;
typedef __attribute__((ext_vector_type(4)))  unsigned short u16x4;

static __device__ __forceinline__ u16 f2bf(float f) {
    unsigned int u = __float_as_uint(f);
    unsigned int r = (u + 0x7FFFu + ((u >> 16) & 1u)) >> 16;   // RNE
    return (u16)r;
}
static __device__ __forceinline__ float bf2f(u16 h) {
    return __uint_as_float(((unsigned int)h) << 16);
}
// involution swizzle on byte offsets within an 8KB [128 rows x 64B] LDS array
static __device__ __forceinline__ int swz(int a) {
    return a ^ (((a >> 7) & 3) << 4);
}
static __device__ __forceinline__ void gload16(const void* g, void* l) {
    __builtin_amdgcn_global_load_lds(
        (const __attribute__((address_space(1))) unsigned int*)g,
        (__attribute__((address_space(3))) unsigned int*)l, 16, 0, 0);
}

// ---------------------------------------------------------------------------
// prep: [0,2048) split x; [2048,2144) W transpose+split; [2144,2208) zero cnt
// ---------------------------------------------------------------------------
__global__ __launch_bounds__(256) void prep_kernel(
    const float* __restrict__ x, const float* __restrict__ Wl,
    const float* __restrict__ Wr,
    u16* __restrict__ Xhi, u16* __restrict__ Xlo,
    u16* __restrict__ WtL_hi, u16* __restrict__ WtL_lo,
    u16* __restrict__ WtR_hi, u16* __restrict__ WtR_lo,
    int* __restrict__ cnt)
{
    __shared__ float S[64][68];
    const int bid = blockIdx.x;
    const int t = threadIdx.x;
    if (bid < 2048) {
        size_t e0 = ((size_t)bid * 256 + t) * 8;
        float4 v0 = *(const float4*)&x[e0];
        float4 v1 = *(const float4*)&x[e0 + 4];
        float xs[8] = {v0.x, v0.y, v0.z, v0.w, v1.x, v1.y, v1.z, v1.w};
        u16x8 H, L;
        #pragma unroll
        for (int j = 0; j < 8; ++j) {
            u16 h = f2bf(xs[j]);
            H[j] = h; L[j] = f2bf(xs[j] - bf2f(h));
        }
        *(u16x8*)&Xhi[e0] = H;
        *(u16x8*)&Xlo[e0] = L;
    } else if (bid < 2144) {
        int mb = bid - 2048;
        int mat = mb / 16, sub = mb % 16;
        int kt = (sub >> 2) * 64, nt = (sub & 3) * 64;
        const float* src = (mat < 3) ? Wl + (size_t)mat * 65536 : Wr + (size_t)(mat - 3) * 65536;
        u16* dhi = (mat < 3) ? WtL_hi + (size_t)mat * 65536 : WtR_hi + (size_t)(mat - 3) * 65536;
        u16* dlo = (mat < 3) ? WtL_lo + (size_t)mat * 65536 : WtR_lo + (size_t)(mat - 3) * 65536;
        int r = t >> 2, c0 = (t & 3) * 16;
        #pragma unroll
        for (int j = 0; j < 4; ++j) {
            float4 v = *(const float4*)&src[(size_t)(kt + r) * 256 + nt + c0 + j * 4];
            *(float4*)&S[r][c0 + j * 4] = v;
        }
        __syncthreads();
        int n = t >> 2, kc = (t & 3) * 16;
        u16x8 h0, h1, l0, l1;
        #pragma unroll
        for (int j = 0; j < 8; ++j) {
            float xv = S[kc + j][n];
            u16 h = f2bf(xv);
            h0[j] = h; l0[j] = f2bf(xv - bf2f(h));
            float y = S[kc + 8 + j][n];
            u16 g = f2bf(y);
            h1[j] = g; l1[j] = f2bf(y - bf2f(g));
        }
        size_t o = (size_t)(nt + n) * 256 + kt + kc;
        *(u16x8*)&dhi[o] = h0; *(u16x8*)&dhi[o + 8] = h1;
        *(u16x8*)&dlo[o] = l0; *(u16x8*)&dlo[o + 8] = l1;
    } else {
        cnt[(bid - 2144) * 256 + t] = 0;
    }
}

// ---------------------------------------------------------------------------
// bucket fill (plain)
// ---------------------------------------------------------------------------
__global__ __launch_bounds__(256) void fill_bucket_kernel(const int* __restrict__ edge,
                                                          int* __restrict__ cnt,
                                                          int* __restrict__ col) {
    int e = blockIdx.x * 256 + threadIdx.x;
    int dst = edge[N_EDGES + e];
    int src = edge[e];
    int slot = atomicAdd(&cnt[dst], 1);
    if (slot < MAXDEG) col[dst * MAXDEG + slot] = src;
}

// ---------------------------------------------------------------------------
// per-node mean-aggregate (64-lane wave), gathers HI only, writes hi/lo
// ---------------------------------------------------------------------------
static __device__ __forceinline__ void agg_node(const u16* __restrict__ Xs,
                                                const int* __restrict__ cnt,
                                                const int* __restrict__ col,
                                                int node, int lane,
                                                u16* __restrict__ Ah,
                                                u16* __restrict__ Al) {
    int c = cnt[node];
    if (c > MAXDEG) c = MAXDEG;
    int my = (lane < c) ? col[node * MAXDEG + lane] : 0;
    float a0 = 0.f, a1 = 0.f, a2 = 0.f, a3 = 0.f;
    int j = 0;
    for (; j + 8 <= c; j += 8) {
        u16x4 v[8];
        #pragma unroll
        for (int q = 0; q < 8; ++q) {
            int s = __shfl(my, j + q);
            v[q] = *(const u16x4*)&Xs[(size_t)s * D + lane * 4];
        }
        #pragma unroll
        for (int q = 0; q < 8; ++q) {
            a0 += bf2f(v[q][0]); a1 += bf2f(v[q][1]);
            a2 += bf2f(v[q][2]); a3 += bf2f(v[q][3]);
        }
    }
    for (; j < c; ++j) {
        int s = __shfl(my, j);
        u16x4 v = *(const u16x4*)&Xs[(size_t)s * D + lane * 4];
        a0 += bf2f(v[0]); a1 += bf2f(v[1]); a2 += bf2f(v[2]); a3 += bf2f(v[3]);
    }
    float id = 1.0f / (float)(c < 1 ? 1 : c);
    float m[4] = {a0 * id, a1 * id, a2 * id, a3 * id};
    u16x4 H, L;
    #pragma unroll
    for (int q = 0; q < 4; ++q) {
        u16 h = f2bf(m[q]);
        H[q] = h; L[q] = f2bf(m[q] - bf2f(h));
    }
    *(u16x4*)&Ah[(size_t)node * D + lane * 4] = H;
    *(u16x4*)&Al[(size_t)node * D + lane * 4] = L;
}

// ---------------------------------------------------------------------------
// full-graph aggregation (layer 1)
// ---------------------------------------------------------------------------
__global__ __launch_bounds__(256) void agg_kernel(const u16* __restrict__ Xhi,
                                                  const int* __restrict__ cnt,
                                                  const int* __restrict__ col,
                                                  u16* __restrict__ Agghi,
                                                  u16* __restrict__ Agglo) {
    int node = blockIdx.x * 4 + (threadIdx.x >> 6);
    agg_node(Xhi, cnt, col, node, threadIdx.x & 63, Agghi, Agglo);
}

// ---------------------------------------------------------------------------
// full MFMA dual GEMM (layer 1) — R4/R6/R8 proven
// ---------------------------------------------------------------------------
__global__ __launch_bounds__(256) void gemm_mfma_kernel(
    const u16* __restrict__ Xhi,   const u16* __restrict__ Xlo,
    const u16* __restrict__ Agghi, const u16* __restrict__ Agglo,
    const u16* __restrict__ WtRhi, const u16* __restrict__ WtRlo,
    const u16* __restrict__ WtLhi, const u16* __restrict__ WtLlo,
    const float* __restrict__ bias,
    u16* __restrict__ Xohi, u16* __restrict__ Xolo)
{
    __shared__ u16 lds[2][4][4096];   // [buf][Ahi,Alo,Bhi,Blo][8KB]

    const int tid  = threadIdx.x;
    const int w    = tid >> 6, lane = tid & 63;
    const int wm   = w >> 1, wn = w & 1;
    const int bid  = blockIdx.x;
    const int m0   = (bid >> 1) * 128;
    const int n0   = (bid & 1) * 128;

    f32x16 acc[4];
    #pragma unroll
    for (int f = 0; f < 4; ++f)
        #pragma unroll
        for (int j = 0; j < 16; ++j) acc[f][j] = 0.f;

    const int r32 = lane & 31;
    const int khb = (lane >> 5) * 16;

    auto stage = [&](int buf, int tt) {
        const u16* src; int rbase;
        const int k0 = (tt & 7) * 32;
        const bool ph2 = tt >= 8;
        if      (w == 0) { src = ph2 ? Agghi : Xhi;  rbase = m0; }
        else if (w == 1) { src = ph2 ? Agglo : Xlo;  rbase = m0; }
        else if (w == 2) { src = ph2 ? WtLhi : WtRhi; rbase = n0; }
        else             { src = ph2 ? WtLlo : WtRlo; rbase = n0; }
        char* base = (char*)&lds[buf][w][0];
        #pragma unroll
        for (int i = 0; i < 8; ++i) {
            int o = i * 1024 + lane * 16;
            int a = swz(o);
            const u16* g = src + (size_t)(rbase + (a >> 6)) * D + k0 + ((a & 63) >> 1);
            gload16(g, base + i * 1024);
        }
    };

    auto compute = [&](int buf) {
        const char* Ah = (const char*)&lds[buf][0][0];
        const char* Al = (const char*)&lds[buf][1][0];
        const char* Bh = (const char*)&lds[buf][2][0];
        const char* Bl = (const char*)&lds[buf][3][0];
        #pragma unroll
        for (int s = 0; s < 2; ++s) {
            const int cb = s * 32 + khb;
            const int ra0 = wm * 64 + r32, ra1 = ra0 + 32;
            const int rb0 = wn * 64 + r32, rb1 = rb0 + 32;
            bf16x8 ah0 = *(const bf16x8*)(Ah + swz(ra0 * 64 + cb));
            bf16x8 ah1 = *(const bf16x8*)(Ah + swz(ra1 * 64 + cb));
            bf16x8 al0 = *(const bf16x8*)(Al + swz(ra0 * 64 + cb));
            bf16x8 al1 = *(const bf16x8*)(Al + swz(ra1 * 64 + cb));
            bf16x8 bh0 = *(const bf16x8*)(Bh + swz(rb0 * 64 + cb));
            bf16x8 bh1 = *(const bf16x8*)(Bh + swz(rb1 * 64 + cb));
            bf16x8 bl0 = *(const bf16x8*)(Bl + swz(rb0 * 64 + cb));
            bf16x8 bl1 = *(const bf16x8*)(Bl + swz(rb1 * 64 + cb));
            acc[0] = __builtin_amdgcn_mfma_f32_32x32x16_bf16(ah0, bh0, acc[0], 0, 0, 0);
            acc[1] = __builtin_amdgcn_mfma_f32_32x32x16_bf16(ah0, bh1, acc[1], 0, 0, 0);
            acc[2] = __builtin_amdgcn_mfma_f32_32x32x16_bf16(ah1, bh0, acc[2], 0, 0, 0);
            acc[3] = __builtin_amdgcn_mfma_f32_32x32x16_bf16(ah1, bh1, acc[3], 0, 0, 0);
            acc[0] = __builtin_amdgcn_mfma_f32_32x32x16_bf16(al0, bh0, acc[0], 0, 0, 0);
            acc[1] = __builtin_amdgcn_mfma_f32_32x32x16_bf16(al0, bh1, acc[1], 0, 0, 0);
            acc[2] = __builtin_amdgcn_mfma_f32_32x32x16_bf16(al1, bh0, acc[2], 0, 0, 0);
            acc[3] = __builtin_amdgcn_mfma_f32_32x32x16_bf16(al1, bh1, acc[3], 0, 0, 0);
            acc[0] = __builtin_amdgcn_mfma_f32_32x32x16_bf16(ah0, bl0, acc[0], 0, 0, 0);
            acc[1] = __builtin_amdgcn_mfma_f32_32x32x16_bf16(ah0, bl1, acc[1], 0, 0, 0);
            acc[2] = __builtin_amdgcn_mfma_f32_32x32x16_bf16(ah1, bl0, acc[2], 0, 0, 0);
            acc[3] = __builtin_amdgcn_mfma_f32_32x32x16_bf16(ah1, bl1, acc[3], 0, 0, 0);
        }
    };

    stage(0, 0);
    __syncthreads();
    int cur = 0;
    for (int t = 0; t < 16; ++t) {
        if (t < 15) stage(cur ^ 1, t + 1);
        compute(cur);
        __syncthreads();
        cur ^= 1;
    }

    #pragma unroll
    for (int fm = 0; fm < 2; ++fm) {
        #pragma unroll
        for (int fn = 0; fn < 2; ++fn) {
            const int colc = n0 + wn * 64 + fn * 32 + r32;
            const int rowb = m0 + wm * 64 + fm * 32 + 4 * (lane >> 5);
            const float bv = bias[colc];
            #pragma unroll
            for (int reg = 0; reg < 16; ++reg) {
                const int row = rowb + (reg & 3) + 8 * (reg >> 2);
                float v = acc[fm * 2 + fn][reg] + bv;
                u16 h = f2bf(v);
                Xohi[(size_t)row * D + colc] = h;
                Xolo[(size_t)row * D + colc] = f2bf(v - bf2f(h));
            }
        }
    }
}

// ---------------------------------------------------------------------------
// Telescoped tail: per root r, compute v0=X1[r], v1=mean_{n in(r)}X1[n],
// v2=mean_{n in(r)} mean_{m in(n)} X1[m]  (2-hop gathers, f32 reconstruct),
// then X2[r]   = v1@Wl2 + v0@Wr2 + b2
//      (AX2)[r]= v2@Wl2 + v1@Wr2 + b2
//      X3[r]   = (AX2)[r]@Wl3 + X2[r]@Wr3 + b3
// then the 3-layer MLP head. One block per graph, 1024 threads, f32 GEMVs.
// ---------------------------------------------------------------------------
__global__ __launch_bounds__(1024) void tail_kernel(
    const int* __restrict__ cnt, const int* __restrict__ col,
    const u16* __restrict__ x1h, const u16* __restrict__ x1l,
    const float* __restrict__ Wl, const float* __restrict__ bl,
    const float* __restrict__ Wr,
    const float* __restrict__ Wh, const float* __restrict__ bh,
    const float* __restrict__ Wo, const float* __restrict__ bo,
    float* __restrict__ out)
{
    __shared__ float v0[D], v1[D], v2[D];
    __shared__ float part1[16][D];
    __shared__ float part2[16][D];
    __shared__ float pA[4][D], pB[4][D];
    __shared__ float hA[D], hB[D];
    __shared__ int nbr[MAXDEG];
    __shared__ int snr;

    const int b = blockIdx.x, t = threadIdx.x;
    const int w = t >> 6, lane = t & 63;
    const int root = b * NODES_PER_GRAPH;

    if (t == 0) { int cc = cnt[root]; snr = (cc > MAXDEG) ? MAXDEG : cc; }
    __syncthreads();
    const int c0 = snr;
    if (t < c0) nbr[t] = col[root * MAXDEG + t];
    if (t < D) {
        size_t idx = (size_t)root * D + t;
        v0[t] = bf2f(x1h[idx]) + bf2f(x1l[idx]);
    }
    __syncthreads();

    // wave w owns first-hop neighbors i = w, w+16, ...; register partials
    float p1[4] = {0.f, 0.f, 0.f, 0.f}, p2[4] = {0.f, 0.f, 0.f, 0.f};
    for (int i = w; i < c0; i += 16) {
        int n = nbr[i];
        {   // X1[n] into p1
            size_t idx = (size_t)n * D + lane * 4;
            u16x4 vh = *(const u16x4*)&x1h[idx];
            u16x4 vl = *(const u16x4*)&x1l[idx];
            #pragma unroll
            for (int q = 0; q < 4; ++q) p1[q] += bf2f(vh[q]) + bf2f(vl[q]);
        }
        // u = mean over in(n) of X1[m] (f32), into p2
        int c = cnt[n]; if (c > MAXDEG) c = MAXDEG;
        int my = (lane < c) ? col[n * MAXDEG + lane] : 0;
        float a[4] = {0.f, 0.f, 0.f, 0.f};
        int j = 0;
        for (; j + 4 <= c; j += 4) {
            u16x4 vh[4], vl[4];
            #pragma unroll
            for (int q = 0; q < 4; ++q) {
                int s = __shfl(my, j + q);
                size_t idx = (size_t)s * D + lane * 4;
                vh[q] = *(const u16x4*)&x1h[idx];
                vl[q] = *(const u16x4*)&x1l[idx];
            }
            #pragma unroll
            for (int q = 0; q < 4; ++q) {
                a[0] += bf2f(vh[q][0]) + bf2f(vl[q][0]);
                a[1] += bf2f(vh[q][1]) + bf2f(vl[q][1]);
                a[2] += bf2f(vh[q][2]) + bf2f(vl[q][2]);
                a[3] += bf2f(vh[q][3]) + bf2f(vl[q][3]);
            }
        }
        for (; j < c; ++j) {
            int s = __shfl(my, j);
            size_t idx = (size_t)s * D + lane * 4;
            u16x4 vh = *(const u16x4*)&x1h[idx];
            u16x4 vl = *(const u16x4*)&x1l[idx];
            a[0] += bf2f(vh[0]) + bf2f(vl[0]);
            a[1] += bf2f(vh[1]) + bf2f(vl[1]);
            a[2] += bf2f(vh[2]) + bf2f(vl[2]);
            a[3] += bf2f(vh[3]) + bf2f(vl[3]);
        }
        float id = 1.0f / (float)(c < 1 ? 1 : c);
        #pragma unroll
        for (int q = 0; q < 4; ++q) p2[q] += a[q] * id;
    }
    #pragma unroll
    for (int q = 0; q < 4; ++q) {
        part1[w][lane * 4 + q] = p1[q];
        part2[w][lane * 4 + q] = p2[q];
    }
    __syncthreads();
    if (t < D) {
        float s1 = 0.f, s2 = 0.f;
        #pragma unroll
        for (int ww = 0; ww < 16; ++ww) { s1 += part1[ww][t]; s2 += part2[ww][t]; }
        float id0 = 1.0f / (float)(c0 < 1 ? 1 : c0);
        v1[t] = s1 * id0;
        v2[t] = s2 * id0;
    }
    __syncthreads();

    const int c = t & 255, kq = t >> 8;
    // layer 2: hA = v2@Wl2 + v1@Wr2 + b2 ; hB = v1@Wl2 + v0@Wr2 + b2
    {
        const float* WL = Wl + (size_t)1 * D * D;
        const float* WR = Wr + (size_t)1 * D * D;
        float aA = 0.f, aB = 0.f;
        #pragma unroll 8
        for (int k0 = 0; k0 < 64; ++k0) {
            int k = kq * 64 + k0;
            float wl = WL[(size_t)k * D + c];
            float wr = WR[(size_t)k * D + c];
            aA += v2[k] * wl + v1[k] * wr;
            aB += v1[k] * wl + v0[k] * wr;
        }
        pA[kq][c] = aA; pB[kq][c] = aB;
        __syncthreads();
        if (t < D) {
            float bb = bl[D + t];
            hA[t] = pA[0][t] + pA[1][t] + pA[2][t] + pA[3][t] + bb;
            hB[t] = pB[0][t] + pB[1][t] + pB[2][t] + pB[3][t] + bb;
        }
        __syncthreads();
    }
    // layer 3: v0 <- hA@Wl3 + hB@Wr3 + b3   (= X3[root], head input)
    {
        const float* WL = Wl + (size_t)2 * D * D;
        const float* WR = Wr + (size_t)2 * D * D;
        float acc = 0.f;
        #pragma unroll 8
        for (int k0 = 0; k0 < 64; ++k0) {
            int k = kq * 64 + k0;
            acc += hA[k] * WL[(size_t)k * D + c] + hB[k] * WR[(size_t)k * D + c];
        }
        pA[kq][c] = acc;
        __syncthreads();
        if (t < D) v0[t] = pA[0][t] + pA[1][t] + pA[2][t] + pA[3][t] + bl[2 * D + t];
        __syncthreads();
    }
    // MLP head
    for (int l = 0; l < 3; ++l) {
        const float* W = (l < 2) ? Wh + (size_t)l * D * D : Wo;
        float acc = 0.f;
        #pragma unroll 8
        for (int k0 = 0; k0 < 64; ++k0) {
            int k = kq * 64 + k0;
            acc += v0[k] * W[(size_t)k * D + c];
        }
        pA[kq][c] = acc;
        __syncthreads();
        if (t < D) {
            float v = pA[0][t] + pA[1][t] + pA[2][t] + pA[3][t]
                    + ((l < 2) ? bh[(size_t)l * D + t] : bo[t]);
            if (l < 2) v0[t] = fmaxf(v, 0.f);
            else       out[(size_t)b * D + t] = v;
        }
        __syncthreads();
    }
}

// ---------------------------------------------------------------------------
extern "C" void kernel_launch(void* const* d_in, const int* in_sizes, int n_in,
                              void* d_out, int out_size, void* d_ws, size_t ws_size,
                              hipStream_t stream) {
    const float* x    = (const float*)d_in[0];
    const int*   edge = (const int*)d_in[1];
    const float* Wl   = (const float*)d_in[2];
    const float* bl   = (const float*)d_in[3];
    const float* Wr   = (const float*)d_in[4];
    const float* Wh   = (const float*)d_in[5];
    const float* bh   = (const float*)d_in[6];
    const float* Wo   = (const float*)d_in[7];
    const float* bo   = (const float*)d_in[8];
    float* out = (float*)d_out;

    char* w = (char*)d_ws;
    auto alloc = [&](size_t bytes) {
        char* p = w;
        w += (bytes + 255) & ~(size_t)255;
        return p;
    };
    int* cnt = (int*)alloc((size_t)N_NODES * 4);
    int* col = (int*)alloc((size_t)N_NODES * MAXDEG * 4);
    u16* X0h = (u16*)alloc((size_t)N_NODES * D * 2);
    u16* X0l = (u16*)alloc((size_t)N_NODES * D * 2);
    u16* X1h = (u16*)alloc((size_t)N_NODES * D * 2);
    u16* X1l = (u16*)alloc((size_t)N_NODES * D * 2);
    u16* Agghi = (u16*)alloc((size_t)N_NODES * D * 2);
    u16* Agglo = (u16*)alloc((size_t)N_NODES * D * 2);
    u16* WtLhi = (u16*)alloc((size_t)3 * 65536 * 2);
    u16* WtLlo = (u16*)alloc((size_t)3 * 65536 * 2);
    u16* WtRhi = (u16*)alloc((size_t)3 * 65536 * 2);
    u16* WtRlo = (u16*)alloc((size_t)3 * 65536 * 2);

    prep_kernel<<<2208, 256, 0, stream>>>(x, Wl, Wr, X0h, X0l,
                                          WtLhi, WtLlo, WtRhi, WtRlo, cnt);
    fill_bucket_kernel<<<N_EDGES / 256, 256, 0, stream>>>(edge, cnt, col);
    // ---- layer 1: full graph ----
    agg_kernel<<<N_NODES / 4, 256, 0, stream>>>(X0h, cnt, col, Agghi, Agglo);
    gemm_mfma_kernel<<<256, 256, 0, stream>>>(
        X0h, X0l, Agghi, Agglo,
        WtRhi, WtRlo, WtLhi, WtLlo,
        bl, X1h, X1l);
    // ---- layers 2+3 + head: telescoped per-root tail ----
    tail_kernel<<<B_GRAPHS, 1024, 0, stream>>>(
        cnt, col, X1h, X1l,
        Wl, bl, Wr, Wh, bh, Wo, bo, out);
}

// Round 13
// 97.441 us; speedup vs baseline: 1.4890x; 1.0042x over previous
//
#include <hip/hip_runtime.h>

#define N_NODES 16384
#define N_EDGES 262144
#define D 256
#define B_GRAPHS 32
#define NODES_PER_GRAPH 512   // N_NODES / B_GRAPHS
#define MAXDEG 64             // Poisson(16): P(deg>64) ~ 1e-17

typedef unsigned short u16;
typedef __attribute__((ext_vector_type(8)))  short bf16x8;
typedef __attribute__((ext_vector_type(16))) float f32x16;
typedef __attribute__((ext_vector_type(8)))  unsigned short u16x8;
typedef __attribute__((ext_vector_type(4)))  unsigned short u16x4;

static __device__ __forceinline__ u16 f2bf(float f) {
    unsigned int u = __float_as_uint(f);
    unsigned int r = (u + 0x7FFFu + ((u >> 16) & 1u)) >> 16;   // RNE
    return (u16)r;
}
static __device__ __forceinline__ float bf2f(u16 h) {
    return __uint_as_float(((unsigned int)h) << 16);
}
// involution swizzle on byte offsets within an 8KB [128 rows x 64B] LDS array
static __device__ __forceinline__ int swz(int a) {
    return a ^ (((a >> 7) & 3) << 4);
}
static __device__ __forceinline__ void gload16(const void* g, void* l) {
    __builtin_amdgcn_global_load_lds(
        (const __attribute__((address_space(1))) unsigned int*)g,
        (__attribute__((address_space(3))) unsigned int*)l, 16, 0, 0);
}

// ---------------------------------------------------------------------------
// prep: [0,2048) split x; [2048,2144) W transpose+split; [2144,2208) zero cnt
// ---------------------------------------------------------------------------
__global__ __launch_bounds__(256) void prep_kernel(
    const float* __restrict__ x, const float* __restrict__ Wl,
    const float* __restrict__ Wr,
    u16* __restrict__ Xhi, u16* __restrict__ Xlo,
    u16* __restrict__ WtL_hi, u16* __restrict__ WtL_lo,
    u16* __restrict__ WtR_hi, u16* __restrict__ WtR_lo,
    int* __restrict__ cnt)
{
    __shared__ float S[64][68];
    const int bid = blockIdx.x;
    const int t = threadIdx.x;
    if (bid < 2048) {
        size_t e0 = ((size_t)bid * 256 + t) * 8;
        float4 v0 = *(const float4*)&x[e0];
        float4 v1 = *(const float4*)&x[e0 + 4];
        float xs[8] = {v0.x, v0.y, v0.z, v0.w, v1.x, v1.y, v1.z, v1.w};
        u16x8 H, L;
        #pragma unroll
        for (int j = 0; j < 8; ++j) {
            u16 h = f2bf(xs[j]);
            H[j] = h; L[j] = f2bf(xs[j] - bf2f(h));
        }
        *(u16x8*)&Xhi[e0] = H;
        *(u16x8*)&Xlo[e0] = L;
    } else if (bid < 2144) {
        int mb = bid - 2048;
        int mat = mb / 16, sub = mb % 16;
        int kt = (sub >> 2) * 64, nt = (sub & 3) * 64;
        const float* src = (mat < 3) ? Wl + (size_t)mat * 65536 : Wr + (size_t)(mat - 3) * 65536;
        u16* dhi = (mat < 3) ? WtL_hi + (size_t)mat * 65536 : WtR_hi + (size_t)(mat - 3) * 65536;
        u16* dlo = (mat < 3) ? WtL_lo + (size_t)mat * 65536 : WtR_lo + (size_t)(mat - 3) * 65536;
        int r = t >> 2, c0 = (t & 3) * 16;
        #pragma unroll
        for (int j = 0; j < 4; ++j) {
            float4 v = *(const float4*)&src[(size_t)(kt + r) * 256 + nt + c0 + j * 4];
            *(float4*)&S[r][c0 + j * 4] = v;
        }
        __syncthreads();
        int n = t >> 2, kc = (t & 3) * 16;
        u16x8 h0, h1, l0, l1;
        #pragma unroll
        for (int j = 0; j < 8; ++j) {
            float xv = S[kc + j][n];
            u16 h = f2bf(xv);
            h0[j] = h; l0[j] = f2bf(xv - bf2f(h));
            float y = S[kc + 8 + j][n];
            u16 g = f2bf(y);
            h1[j] = g; l1[j] = f2bf(y - bf2f(g));
        }
        size_t o = (size_t)(nt + n) * 256 + kt + kc;
        *(u16x8*)&dhi[o] = h0; *(u16x8*)&dhi[o + 8] = h1;
        *(u16x8*)&dlo[o] = l0; *(u16x8*)&dlo[o + 8] = l1;
    } else {
        cnt[(bid - 2144) * 256 + t] = 0;
    }
}

// ---------------------------------------------------------------------------
// bucket fill (plain)
// ---------------------------------------------------------------------------
__global__ __launch_bounds__(256) void fill_bucket_kernel(const int* __restrict__ edge,
                                                          int* __restrict__ cnt,
                                                          int* __restrict__ col) {
    int e = blockIdx.x * 256 + threadIdx.x;
    int dst = edge[N_EDGES + e];
    int src = edge[e];
    int slot = atomicAdd(&cnt[dst], 1);
    if (slot < MAXDEG) col[dst * MAXDEG + slot] = src;
}

// ---------------------------------------------------------------------------
// per-node mean-aggregate (64-lane wave), gathers HI only, writes hi/lo
// ---------------------------------------------------------------------------
static __device__ __forceinline__ void agg_node(const u16* __restrict__ Xs,
                                                const int* __restrict__ cnt,
                                                const int* __restrict__ col,
                                                int node, int lane,
                                                u16* __restrict__ Ah,
                                                u16* __restrict__ Al) {
    int c = cnt[node];
    if (c > MAXDEG) c = MAXDEG;
    int my = (lane < c) ? col[node * MAXDEG + lane] : 0;
    float a0 = 0.f, a1 = 0.f, a2 = 0.f, a3 = 0.f;
    int j = 0;
    for (; j + 8 <= c; j += 8) {
        u16x4 v[8];
        #pragma unroll
        for (int q = 0; q < 8; ++q) {
            int s = __shfl(my, j + q);
            v[q] = *(const u16x4*)&Xs[(size_t)s * D + lane * 4];
        }
        #pragma unroll
        for (int q = 0; q < 8; ++q) {
            a0 += bf2f(v[q][0]); a1 += bf2f(v[q][1]);
            a2 += bf2f(v[q][2]); a3 += bf2f(v[q][3]);
        }
    }
    for (; j < c; ++j) {
        int s = __shfl(my, j);
        u16x4 v = *(const u16x4*)&Xs[(size_t)s * D + lane * 4];
        a0 += bf2f(v[0]); a1 += bf2f(v[1]); a2 += bf2f(v[2]); a3 += bf2f(v[3]);
    }
    float id = 1.0f / (float)(c < 1 ? 1 : c);
    float m[4] = {a0 * id, a1 * id, a2 * id, a3 * id};
    u16x4 H, L;
    #pragma unroll
    for (int q = 0; q < 4; ++q) {
        u16 h = f2bf(m[q]);
        H[q] = h; L[q] = f2bf(m[q] - bf2f(h));
    }
    *(u16x4*)&Ah[(size_t)node * D + lane * 4] = H;
    *(u16x4*)&Al[(size_t)node * D + lane * 4] = L;
}

// ---------------------------------------------------------------------------
// full-graph aggregation (layer 1)
// ---------------------------------------------------------------------------
__global__ __launch_bounds__(256) void agg_kernel(const u16* __restrict__ Xhi,
                                                  const int* __restrict__ cnt,
                                                  const int* __restrict__ col,
                                                  u16* __restrict__ Agghi,
                                                  u16* __restrict__ Agglo) {
    int node = blockIdx.x * 4 + (threadIdx.x >> 6);
    agg_node(Xhi, cnt, col, node, threadIdx.x & 63, Agghi, Agglo);
}

// ---------------------------------------------------------------------------
// full MFMA dual GEMM (layer 1) — R4/R6/R8 proven
// ---------------------------------------------------------------------------
__global__ __launch_bounds__(256) void gemm_mfma_kernel(
    const u16* __restrict__ Xhi,   const u16* __restrict__ Xlo,
    const u16* __restrict__ Agghi, const u16* __restrict__ Agglo,
    const u16* __restrict__ WtRhi, const u16* __restrict__ WtRlo,
    const u16* __restrict__ WtLhi, const u16* __restrict__ WtLlo,
    const float* __restrict__ bias,
    u16* __restrict__ Xohi, u16* __restrict__ Xolo)
{
    __shared__ u16 lds[2][4][4096];   // [buf][Ahi,Alo,Bhi,Blo][8KB]

    const int tid  = threadIdx.x;
    const int w    = tid >> 6, lane = tid & 63;
    const int wm   = w >> 1, wn = w & 1;
    const int bid  = blockIdx.x;
    const int m0   = (bid >> 1) * 128;
    const int n0   = (bid & 1) * 128;

    f32x16 acc[4];
    #pragma unroll
    for (int f = 0; f < 4; ++f)
        #pragma unroll
        for (int j = 0; j < 16; ++j) acc[f][j] = 0.f;

    const int r32 = lane & 31;
    const int khb = (lane >> 5) * 16;

    auto stage = [&](int buf, int tt) {
        const u16* src; int rbase;
        const int k0 = (tt & 7) * 32;
        const bool ph2 = tt >= 8;
        if      (w == 0) { src = ph2 ? Agghi : Xhi;  rbase = m0; }
        else if (w == 1) { src = ph2 ? Agglo : Xlo;  rbase = m0; }
        else if (w == 2) { src = ph2 ? WtLhi : WtRhi; rbase = n0; }
        else             { src = ph2 ? WtLlo : WtRlo; rbase = n0; }
        char* base = (char*)&lds[buf][w][0];
        #pragma unroll
        for (int i = 0; i < 8; ++i) {
            int o = i * 1024 + lane * 16;
            int a = swz(o);
            const u16* g = src + (size_t)(rbase + (a >> 6)) * D + k0 + ((a & 63) >> 1);
            gload16(g, base + i * 1024);
        }
    };

    auto compute = [&](int buf) {
        const char* Ah = (const char*)&lds[buf][0][0];
        const char* Al = (const char*)&lds[buf][1][0];
        const char* Bh = (const char*)&lds[buf][2][0];
        const char* Bl = (const char*)&lds[buf][3][0];
        #pragma unroll
        for (int s = 0; s < 2; ++s) {
            const int cb = s * 32 + khb;
            const int ra0 = wm * 64 + r32, ra1 = ra0 + 32;
            const int rb0 = wn * 64 + r32, rb1 = rb0 + 32;
            bf16x8 ah0 = *(const bf16x8*)(Ah + swz(ra0 * 64 + cb));
            bf16x8 ah1 = *(const bf16x8*)(Ah + swz(ra1 * 64 + cb));
            bf16x8 al0 = *(const bf16x8*)(Al + swz(ra0 * 64 + cb));
            bf16x8 al1 = *(const bf16x8*)(Al + swz(ra1 * 64 + cb));
            bf16x8 bh0 = *(const bf16x8*)(Bh + swz(rb0 * 64 + cb));
            bf16x8 bh1 = *(const bf16x8*)(Bh + swz(rb1 * 64 + cb));
            bf16x8 bl0 = *(const bf16x8*)(Bl + swz(rb0 * 64 + cb));
            bf16x8 bl1 = *(const bf16x8*)(Bl + swz(rb1 * 64 + cb));
            acc[0] = __builtin_amdgcn_mfma_f32_32x32x16_bf16(ah0, bh0, acc[0], 0, 0, 0);
            acc[1] = __builtin_amdgcn_mfma_f32_32x32x16_bf16(ah0, bh1, acc[1], 0, 0, 0);
            acc[2] = __builtin_amdgcn_mfma_f32_32x32x16_bf16(ah1, bh0, acc[2], 0, 0, 0);
            acc[3] = __builtin_amdgcn_mfma_f32_32x32x16_bf16(ah1, bh1, acc[3], 0, 0, 0);
            acc[0] = __builtin_amdgcn_mfma_f32_32x32x16_bf16(al0, bh0, acc[0], 0, 0, 0);
            acc[1] = __builtin_amdgcn_mfma_f32_32x32x16_bf16(al0, bh1, acc[1], 0, 0, 0);
            acc[2] = __builtin_amdgcn_mfma_f32_32x32x16_bf16(al1, bh0, acc[2], 0, 0, 0);
            acc[3] = __builtin_amdgcn_mfma_f32_32x32x16_bf16(al1, bh1, acc[3], 0, 0, 0);
            acc[0] = __builtin_amdgcn_mfma_f32_32x32x16_bf16(ah0, bl0, acc[0], 0, 0, 0);
            acc[1] = __builtin_amdgcn_mfma_f32_32x32x16_bf16(ah0, bl1, acc[1], 0, 0, 0);
            acc[2] = __builtin_amdgcn_mfma_f32_32x32x16_bf16(ah1, bl0, acc[2], 0, 0, 0);
            acc[3] = __builtin_amdgcn_mfma_f32_32x32x16_bf16(ah1, bl1, acc[3], 0, 0, 0);
        }
    };

    stage(0, 0);
    __syncthreads();
    int cur = 0;
    for (int t = 0; t < 16; ++t) {
        if (t < 15) stage(cur ^ 1, t + 1);
        compute(cur);
        __syncthreads();
        cur ^= 1;
    }

    #pragma unroll
    for (int fm = 0; fm < 2; ++fm) {
        #pragma unroll
        for (int fn = 0; fn < 2; ++fn) {
            const int colc = n0 + wn * 64 + fn * 32 + r32;
            const int rowb = m0 + wm * 64 + fm * 32 + 4 * (lane >> 5);
            const float bv = bias[colc];
            #pragma unroll
            for (int reg = 0; reg < 16; ++reg) {
                const int row = rowb + (reg & 3) + 8 * (reg >> 2);
                float v = acc[fm * 2 + fn][reg] + bv;
                u16 h = f2bf(v);
                Xohi[(size_t)row * D + colc] = h;
                Xolo[(size_t)row * D + colc] = f2bf(v - bf2f(h));
            }
        }
    }
}

// ---------------------------------------------------------------------------
// Telescoped tail: per root r, compute v0=X1[r], v1=mean_{n in(r)}X1[n],
// v2=mean_{n in(r)} mean_{m in(n)} X1[m]  (2-hop gathers, f32 reconstruct),
// then X2[r]   = v1@Wl2 + v0@Wr2 + b2
//      (AX2)[r]= v2@Wl2 + v1@Wr2 + b2
//      X3[r]   = (AX2)[r]@Wl3 + X2[r]@Wr3 + b3
// then the 3-layer MLP head. One block per graph, 1024 threads, f32 GEMVs.
// ---------------------------------------------------------------------------
__global__ __launch_bounds__(1024) void tail_kernel(
    const int* __restrict__ cnt, const int* __restrict__ col,
    const u16* __restrict__ x1h, const u16* __restrict__ x1l,
    const float* __restrict__ Wl, const float* __restrict__ bl,
    const float* __restrict__ Wr,
    const float* __restrict__ Wh, const float* __restrict__ bh,
    const float* __restrict__ Wo, const float* __restrict__ bo,
    float* __restrict__ out)
{
    __shared__ float v0[D], v1[D], v2[D];
    __shared__ float part1[16][D];
    __shared__ float part2[16][D];
    __shared__ float pA[4][D], pB[4][D];
    __shared__ float hA[D], hB[D];
    __shared__ int nbr[MAXDEG];
    __shared__ int snr;

    const int b = blockIdx.x, t = threadIdx.x;
    const int w = t >> 6, lane = t & 63;
    const int root = b * NODES_PER_GRAPH;

    if (t == 0) { int cc = cnt[root]; snr = (cc > MAXDEG) ? MAXDEG : cc; }
    __syncthreads();
    const int c0 = snr;
    if (t < c0) nbr[t] = col[root * MAXDEG + t];
    if (t < D) {
        size_t idx = (size_t)root * D + t;
        v0[t] = bf2f(x1h[idx]) + bf2f(x1l[idx]);
    }
    __syncthreads();

    // wave w owns first-hop neighbors i = w, w+16, ...; register partials
    float p1[4] = {0.f, 0.f, 0.f, 0.f}, p2[4] = {0.f, 0.f, 0.f, 0.f};
    for (int i = w; i < c0; i += 16) {
        int n = nbr[i];
        {   // X1[n] into p1
            size_t idx = (size_t)n * D + lane * 4;
            u16x4 vh = *(const u16x4*)&x1h[idx];
            u16x4 vl = *(const u16x4*)&x1l[idx];
            #pragma unroll
            for (int q = 0; q < 4; ++q) p1[q] += bf2f(vh[q]) + bf2f(vl[q]);
        }
        // u = mean over in(n) of X1[m] (f32), into p2
        int c = cnt[n]; if (c > MAXDEG) c = MAXDEG;
        int my = (lane < c) ? col[n * MAXDEG + lane] : 0;
        float a[4] = {0.f, 0.f, 0.f, 0.f};
        int j = 0;
        for (; j + 4 <= c; j += 4) {
            u16x4 vh[4], vl[4];
            #pragma unroll
            for (int q = 0; q < 4; ++q) {
                int s = __shfl(my, j + q);
                size_t idx = (size_t)s * D + lane * 4;
                vh[q] = *(const u16x4*)&x1h[idx];
                vl[q] = *(const u16x4*)&x1l[idx];
            }
            #pragma unroll
            for (int q = 0; q < 4; ++q) {
                a[0] += bf2f(vh[q][0]) + bf2f(vl[q][0]);
                a[1] += bf2f(vh[q][1]) + bf2f(vl[q][1]);
                a[2] += bf2f(vh[q][2]) + bf2f(vl[q][2]);
                a[3] += bf2f(vh[q][3]) + bf2f(vl[q][3]);
            }
        }
        for (; j < c; ++j) {
            int s = __shfl(my, j);
            size_t idx = (size_t)s * D + lane * 4;
            u16x4 vh = *(const u16x4*)&x1h[idx];
            u16x4 vl = *(const u16x4*)&x1l[idx];
            a[0] += bf2f(vh[0]) + bf2f(vl[0]);
            a[1] += bf2f(vh[1]) + bf2f(vl[1]);
            a[2] += bf2f(vh[2]) + bf2f(vl[2]);
            a[3] += bf2f(vh[3]) + bf2f(vl[3]);
        }
        float id = 1.0f / (float)(c < 1 ? 1 : c);
        #pragma unroll
        for (int q = 0; q < 4; ++q) p2[q] += a[q] * id;
    }
    #pragma unroll
    for (int q = 0; q < 4; ++q) {
        part1[w][lane * 4 + q] = p1[q];
        part2[w][lane * 4 + q] = p2[q];
    }
    __syncthreads();
    if (t < D) {
        float s1 = 0.f, s2 = 0.f;
        #pragma unroll
        for (int ww = 0; ww < 16; ++ww) { s1 += part1[ww][t]; s2 += part2[ww][t]; }
        float id0 = 1.0f / (float)(c0 < 1 ? 1 : c0);
        v1[t] = s1 * id0;
        v2[t] = s2 * id0;
    }
    __syncthreads();

    const int c = t & 255, kq = t >> 8;
    // layer 2: hA = v2@Wl2 + v1@Wr2 + b2 ; hB = v1@Wl2 + v0@Wr2 + b2
    {
        const float* WL = Wl + (size_t)1 * D * D;
        const float* WR = Wr + (size_t)1 * D * D;
        float aA = 0.f, aB = 0.f;
        #pragma unroll 8
        for (int k0 = 0; k0 < 64; ++k0) {
            int k = kq * 64 + k0;
            float wl = WL[(size_t)k * D + c];
            float wr = WR[(size_t)k * D + c];
            aA += v2[k] * wl + v1[k] * wr;
            aB += v1[k] * wl + v0[k] * wr;
        }
        pA[kq][c] = aA; pB[kq][c] = aB;
        __syncthreads();
        if (t < D) {
            float bb = bl[D + t];
            hA[t] = pA[0][t] + pA[1][t] + pA[2][t] + pA[3][t] + bb;
            hB[t] = pB[0][t] + pB[1][t] + pB[2][t] + pB[3][t] + bb;
        }
        __syncthreads();
    }
    // layer 3: v0 <- hA@Wl3 + hB@Wr3 + b3   (= X3[root], head input)
    {
        const float* WL = Wl + (size_t)2 * D * D;
        const float* WR = Wr + (size_t)2 * D * D;
        float acc = 0.f;
        #pragma unroll 8
        for (int k0 = 0; k0 < 64; ++k0) {
            int k = kq * 64 + k0;
            acc += hA[k] * WL[(size_t)k * D + c] + hB[k] * WR[(size_t)k * D + c];
        }
        pA[kq][c] = acc;
        __syncthreads();
        if (t < D) v0[t] = pA[0][t] + pA[1][t] + pA[2][t] + pA[3][t] + bl[2 * D + t];
        __syncthreads();
    }
    // MLP head
    for (int l = 0; l < 3; ++l) {
        const float* W = (l < 2) ? Wh + (size_t)l * D * D : Wo;
        float acc = 0.f;
        #pragma unroll 8
        for (int k0 = 0; k0 < 64; ++k0) {
            int k = kq * 64 + k0;
            acc += v0[k] * W[(size_t)k * D + c];
        }
        pA[kq][c] = acc;
        __syncthreads();
        if (t < D) {
            float v = pA[0][t] + pA[1][t] + pA[2][t] + pA[3][t]
                    + ((l < 2) ? bh[(size_t)l * D + t] : bo[t]);
            if (l < 2) v0[t] = fmaxf(v, 0.f);
            else       out[(size_t)b * D + t] = v;
        }
        __syncthreads();
    }
}

// ---------------------------------------------------------------------------
extern "C" void kernel_launch(void* const* d_in, const int* in_sizes, int n_in,
                              void* d_out, int out_size, void* d_ws, size_t ws_size,
                              hipStream_t stream) {
    const float* x    = (const float*)d_in[0];
    const int*   edge = (const int*)d_in[1];
    const float* Wl   = (const float*)d_in[2];
    const float* bl   = (const float*)d_in[3];
    const float* Wr   = (const float*)d_in[4];
    const float* Wh   = (const float*)d_in[5];
    const float* bh   = (const float*)d_in[6];
    const float* Wo   = (const float*)d_in[7];
    const float* bo   = (const float*)d_in[8];
    float* out = (float*)d_out;

    char* w = (char*)d_ws;
    auto alloc = [&](size_t bytes) {
        char* p = w;
        w += (bytes + 255) & ~(size_t)255;
        return p;
    };
    int* cnt = (int*)alloc((size_t)N_NODES * 4);
    int* col = (int*)alloc((size_t)N_NODES * MAXDEG * 4);
    u16* X0h = (u16*)alloc((size_t)N_NODES * D * 2);
    u16* X0l = (u16*)alloc((size_t)N_NODES * D * 2);
    u16* X1h = (u16*)alloc((size_t)N_NODES * D * 2);
    u16* X1l = (u16*)alloc((size_t)N_NODES * D * 2);
    u16* Agghi = (u16*)alloc((size_t)N_NODES * D * 2);
    u16* Agglo = (u16*)alloc((size_t)N_NODES * D * 2);
    u16* WtLhi = (u16*)alloc((size_t)3 * 65536 * 2);
    u16* WtLlo = (u16*)alloc((size_t)3 * 65536 * 2);
    u16* WtRhi = (u16*)alloc((size_t)3 * 65536 * 2);
    u16* WtRlo = (u16*)alloc((size_t)3 * 65536 * 2);

    prep_kernel<<<2208, 256, 0, stream>>>(x, Wl, Wr, X0h, X0l,
                                          WtLhi, WtLlo, WtRhi, WtRlo, cnt);
    fill_bucket_kernel<<<N_EDGES / 256, 256, 0, stream>>>(edge, cnt, col);
    // ---- layer 1: full graph ----
    agg_kernel<<<N_NODES / 4, 256, 0, stream>>>(X0h, cnt, col, Agghi, Agglo);
    gemm_mfma_kernel<<<256, 256, 0, stream>>>(
        X0h, X0l, Agghi, Agglo,
        WtRhi, WtRlo, WtLhi, WtLlo,
        bl, X1h, X1l);
    // ---- layers 2+3 + head: telescoped per-root tail ----
    tail_kernel<<<B_GRAPHS, 1024, 0, stream>>>(
        cnt, col, X1h, X1l,
        Wl, bl, Wr, Wh, bh, Wo, bo, out);
}

// Round 14
// 94.940 us; speedup vs baseline: 1.5283x; 1.0263x over previous
//
#include <hip/hip_runtime.h>

#define N_NODES 16384
#define N_EDGES 262144
#define D 256
#define B_GRAPHS 32
#define NODES_PER_GRAPH 512   // N_NODES / B_GRAPHS
#define MAXDEG 64             // Poisson(16): P(deg>64) ~ 1e-17

// ---------------------------------------------------------------------------
// zero cnt
// ---------------------------------------------------------------------------
__global__ __launch_bounds__(256) void zero_cnt_kernel(int* __restrict__ cnt) {
    cnt[blockIdx.x * 256 + threadIdx.x] = 0;
}

// ---------------------------------------------------------------------------
// bucket fill: col[dst*64 + slot] = src
// ---------------------------------------------------------------------------
__global__ __launch_bounds__(256) void fill_bucket_kernel(const int* __restrict__ edge,
                                                          int* __restrict__ cnt,
                                                          int* __restrict__ col) {
    int e = blockIdx.x * 256 + threadIdx.x;
    int dst = edge[N_EDGES + e];
    int src = edge[e];
    int slot = atomicAdd(&cnt[dst], 1);
    if (slot < MAXDEG) col[dst * MAXDEG + slot] = src;
}

// ---------------------------------------------------------------------------
// aggx: A[i] = mean_{j in in(i)} x[j]   (full graph, f32, one wave per node)
// ---------------------------------------------------------------------------
__global__ __launch_bounds__(256) void aggx_kernel(const float* __restrict__ x,
                                                   const int* __restrict__ cnt,
                                                   const int* __restrict__ col,
                                                   float* __restrict__ A) {
    int node = blockIdx.x * 4 + (threadIdx.x >> 6);
    int lane = threadIdx.x & 63;
    int c = cnt[node];
    if (c > MAXDEG) c = MAXDEG;
    int my = (lane < c) ? col[node * MAXDEG + lane] : 0;
    float a0 = 0.f, a1 = 0.f, a2 = 0.f, a3 = 0.f;
    int j = 0;
    for (; j + 8 <= c; j += 8) {
        float4 v[8];
        #pragma unroll
        for (int q = 0; q < 8; ++q) {
            int s = __shfl(my, j + q);
            v[q] = *(const float4*)&x[(size_t)s * D + lane * 4];
        }
        #pragma unroll
        for (int q = 0; q < 8; ++q) {
            a0 += v[q].x; a1 += v[q].y; a2 += v[q].z; a3 += v[q].w;
        }
    }
    for (; j < c; ++j) {
        int s = __shfl(my, j);
        float4 v = *(const float4*)&x[(size_t)s * D + lane * 4];
        a0 += v.x; a1 += v.y; a2 += v.z; a3 += v.w;
    }
    float id = 1.0f / (float)(c < 1 ? 1 : c);
    float4 r = make_float4(a0 * id, a1 * id, a2 * id, a3 * id);
    *(float4*)&A[(size_t)node * D + lane * 4] = r;
}

// ---------------------------------------------------------------------------
// Fully telescoped tail: one block per graph, 1024 threads, all f32.
// Per root r:
//   g0 = x[r], g1 = A[r], g2 = mean_{n in(r)} A[n],
//   g3 = mean_{n in(r)} mean_{m in(n)} A[m]
//   v0 = g1@Wl1 + g0@Wr1 + b1          (= X1[r])
//   v1 = g2@Wl1 + g1@Wr1 + b1          (= mean_n X1[n])
//   v2 = g3@Wl1 + g2@Wr1 + b1          (= mean_n mean_m X1[m])
//   hB = v1@Wl2 + v0@Wr2 + b2          (= X2[r])
//   hA = v2@Wl2 + v1@Wr2 + b2          (= A3[r])
//   h  = hA@Wl3 + hB@Wr3 + b3          (= X3[r])
//   out = MLP head(h)
// ---------------------------------------------------------------------------
__global__ __launch_bounds__(1024) void tail_kernel(
    const int* __restrict__ cnt, const int* __restrict__ col,
    const float* __restrict__ x, const float* __restrict__ A,
    const float* __restrict__ Wl, const float* __restrict__ bl,
    const float* __restrict__ Wr,
    const float* __restrict__ Wh, const float* __restrict__ bh,
    const float* __restrict__ Wo, const float* __restrict__ bo,
    float* __restrict__ out)
{
    __shared__ float g0[D], g1[D], g2[D], g3[D];
    __shared__ float v0[D], v1[D], v2[D], hA[D], hB[D];
    __shared__ float part1[16][D];     // gather partials (g2) / GEMV partials
    __shared__ float part2[16][D];     // gather partials (g3)
    __shared__ int nbr[MAXDEG];
    __shared__ int snr;

    const int b = blockIdx.x, t = threadIdx.x;
    const int w = t >> 6, lane = t & 63;
    const int root = b * NODES_PER_GRAPH;

    if (t == 0) { int cc = cnt[root]; snr = (cc > MAXDEG) ? MAXDEG : cc; }
    __syncthreads();
    const int c0 = snr;
    if (t < c0) nbr[t] = col[root * MAXDEG + t];
    if (t < D) {
        g0[t] = x[(size_t)root * D + t];
        g1[t] = A[(size_t)root * D + t];
    }
    __syncthreads();

    // ---- 1/2-hop gathers of A: wave w owns neighbors i = w, w+16, ... ----
    float p1[4] = {0.f, 0.f, 0.f, 0.f}, p2[4] = {0.f, 0.f, 0.f, 0.f};
    for (int i = w; i < c0; i += 16) {
        int n = nbr[i];
        {   // A[n] into p1 (for g2)
            float4 v = *(const float4*)&A[(size_t)n * D + lane * 4];
            p1[0] += v.x; p1[1] += v.y; p1[2] += v.z; p1[3] += v.w;
        }
        // inner mean over in(n) of A[m] (for g3)
        int c = cnt[n]; if (c > MAXDEG) c = MAXDEG;
        int my = (lane < c) ? col[n * MAXDEG + lane] : 0;
        float a[4] = {0.f, 0.f, 0.f, 0.f};
        int j = 0;
        for (; j + 4 <= c; j += 4) {
            float4 v[4];
            #pragma unroll
            for (int q = 0; q < 4; ++q) {
                int s = __shfl(my, j + q);
                v[q] = *(const float4*)&A[(size_t)s * D + lane * 4];
            }
            #pragma unroll
            for (int q = 0; q < 4; ++q) {
                a[0] += v[q].x; a[1] += v[q].y; a[2] += v[q].z; a[3] += v[q].w;
            }
        }
        for (; j < c; ++j) {
            int s = __shfl(my, j);
            float4 v = *(const float4*)&A[(size_t)s * D + lane * 4];
            a[0] += v.x; a[1] += v.y; a[2] += v.z; a[3] += v.w;
        }
        float id = 1.0f / (float)(c < 1 ? 1 : c);
        #pragma unroll
        for (int q = 0; q < 4; ++q) p2[q] += a[q] * id;
    }
    #pragma unroll
    for (int q = 0; q < 4; ++q) {
        part1[w][lane * 4 + q] = p1[q];
        part2[w][lane * 4 + q] = p2[q];
    }
    __syncthreads();
    if (t < D) {
        float s1 = 0.f, s2 = 0.f;
        #pragma unroll
        for (int ww = 0; ww < 16; ++ww) { s1 += part1[ww][t]; s2 += part2[ww][t]; }
        float id0 = 1.0f / (float)(c0 < 1 ? 1 : c0);
        g2[t] = s1 * id0;
        g3[t] = s2 * id0;
    }
    __syncthreads();

    const int c = t & 255, kq = t >> 8;
    // ---- layer 1: v0, v1, v2 in one pass over Wl1/Wr1 ----
    {
        const float* WL = Wl;
        const float* WR = Wr;
        float a0 = 0.f, a1 = 0.f, a2 = 0.f;
        #pragma unroll 8
        for (int k0 = 0; k0 < 64; ++k0) {
            int k = kq * 64 + k0;
            float wl = WL[(size_t)k * D + c];
            float wr = WR[(size_t)k * D + c];
            a0 += g1[k] * wl + g0[k] * wr;
            a1 += g2[k] * wl + g1[k] * wr;
            a2 += g3[k] * wl + g2[k] * wr;
        }
        part1[kq][c] = a0; part1[4 + kq][c] = a1; part1[8 + kq][c] = a2;
        __syncthreads();
        if (t < D) {
            float bb = bl[t];
            v0[t] = part1[0][t] + part1[1][t] + part1[2][t] + part1[3][t] + bb;
            v1[t] = part1[4][t] + part1[5][t] + part1[6][t] + part1[7][t] + bb;
            v2[t] = part1[8][t] + part1[9][t] + part1[10][t] + part1[11][t] + bb;
        }
        __syncthreads();
    }
    // ---- layer 2: hA = v2@Wl2 + v1@Wr2 + b2 ; hB = v1@Wl2 + v0@Wr2 + b2 ----
    {
        const float* WL = Wl + (size_t)1 * D * D;
        const float* WR = Wr + (size_t)1 * D * D;
        float aA = 0.f, aB = 0.f;
        #pragma unroll 8
        for (int k0 = 0; k0 < 64; ++k0) {
            int k = kq * 64 + k0;
            float wl = WL[(size_t)k * D + c];
            float wr = WR[(size_t)k * D + c];
            aA += v2[k] * wl + v1[k] * wr;
            aB += v1[k] * wl + v0[k] * wr;
        }
        part1[kq][c] = aA; part1[4 + kq][c] = aB;
        __syncthreads();
        if (t < D) {
            float bb = bl[D + t];
            hA[t] = part1[0][t] + part1[1][t] + part1[2][t] + part1[3][t] + bb;
            hB[t] = part1[4][t] + part1[5][t] + part1[6][t] + part1[7][t] + bb;
        }
        __syncthreads();
    }
    // ---- layer 3: v0 <- hA@Wl3 + hB@Wr3 + b3  (head input) ----
    {
        const float* WL = Wl + (size_t)2 * D * D;
        const float* WR = Wr + (size_t)2 * D * D;
        float acc = 0.f;
        #pragma unroll 8
        for (int k0 = 0; k0 < 64; ++k0) {
            int k = kq * 64 + k0;
            acc += hA[k] * WL[(size_t)k * D + c] + hB[k] * WR[(size_t)k * D + c];
        }
        part1[kq][c] = acc;
        __syncthreads();
        if (t < D) v0[t] = part1[0][t] + part1[1][t] + part1[2][t] + part1[3][t]
                           + bl[2 * D + t];
        __syncthreads();
    }
    // ---- MLP head ----
    for (int l = 0; l < 3; ++l) {
        const float* W = (l < 2) ? Wh + (size_t)l * D * D : Wo;
        float acc = 0.f;
        #pragma unroll 8
        for (int k0 = 0; k0 < 64; ++k0) {
            int k = kq * 64 + k0;
            acc += v0[k] * W[(size_t)k * D + c];
        }
        part1[kq][c] = acc;
        __syncthreads();
        if (t < D) {
            float v = part1[0][t] + part1[1][t] + part1[2][t] + part1[3][t]
                    + ((l < 2) ? bh[(size_t)l * D + t] : bo[t]);
            if (l < 2) v0[t] = fmaxf(v, 0.f);
            else       out[(size_t)b * D + t] = v;
        }
        __syncthreads();
    }
}

// ---------------------------------------------------------------------------
extern "C" void kernel_launch(void* const* d_in, const int* in_sizes, int n_in,
                              void* d_out, int out_size, void* d_ws, size_t ws_size,
                              hipStream_t stream) {
    const float* x    = (const float*)d_in[0];
    const int*   edge = (const int*)d_in[1];
    const float* Wl   = (const float*)d_in[2];
    const float* bl   = (const float*)d_in[3];
    const float* Wr   = (const float*)d_in[4];
    const float* Wh   = (const float*)d_in[5];
    const float* bh   = (const float*)d_in[6];
    const float* Wo   = (const float*)d_in[7];
    const float* bo   = (const float*)d_in[8];
    float* out = (float*)d_out;

    char* w = (char*)d_ws;
    auto alloc = [&](size_t bytes) {
        char* p = w;
        w += (bytes + 255) & ~(size_t)255;
        return p;
    };
    int*   cnt = (int*)  alloc((size_t)N_NODES * 4);
    int*   col = (int*)  alloc((size_t)N_NODES * MAXDEG * 4);
    float* A   = (float*)alloc((size_t)N_NODES * D * 4);

    zero_cnt_kernel<<<N_NODES / 256, 256, 0, stream>>>(cnt);
    fill_bucket_kernel<<<N_EDGES / 256, 256, 0, stream>>>(edge, cnt, col);
    aggx_kernel<<<N_NODES / 4, 256, 0, stream>>>(x, cnt, col, A);
    tail_kernel<<<B_GRAPHS, 1024, 0, stream>>>(cnt, col, x, A,
                                               Wl, bl, Wr, Wh, bh, Wo, bo, out);
}